// Round 1
// baseline (168.962 us; speedup 1.0000x reference)
//
#include <hip/hip_runtime.h>
#include <hip/hip_bf16.h>
#include <stdint.h>

// Problem: out[b,n,o] = sum_t x[b,n,t] * (sum_g y[b,g]*w[g,o,t]*mask[o,t]) + bias[o]
// B=32 N=256 T=1024 O=1024 G=8.  Threshold 0.15375 (bf16-class) -> bf16 MFMA path.
//
// Plan:
//  K1 mix:  Wb[b,o,t] = bf16( mask[o,t] * sum_g y[b,g]*w[g,o,t] )   (ws, 64 MiB)
//  K2 cvt:  xb = bf16(x)                                            (ws, 16 MiB)
//  K3 gemm: out[b] = xb[b] (256x1024) . Wb[b]^T (1024x1024) + bias  (m97 structure)

#define B_ 32
#define N_ 256
#define T_ 1024
#define O_ 1024
#define G_ 8

#define BM 128
#define BN 128
#define BK 32

typedef __attribute__((__ext_vector_type__(8))) __bf16 bf16x8;
typedef __attribute__((__ext_vector_type__(4))) float  f32x4;

__device__ __forceinline__ unsigned short f2bf(float f) {
    union { float f; uint32_t u; } v; v.f = f;
    uint32_t u = v.u;
    uint32_t r = (u + 0x7fffu + ((u >> 16) & 1u)) >> 16;  // round-nearest-even
    return (unsigned short)r;
}

// --- K1: genre-mix + mask, write bf16 Wb[b][o][t].
// One thread handles 4 consecutive t for one o, looping all 32 batches so the
// 33.5 MB weight tensor is read exactly once.
__global__ __launch_bounds__(256) void mix_kernel(
    const float* __restrict__ w,     // [G,O,T]
    const float* __restrict__ mask,  // [O,T]
    const float* __restrict__ y,     // [B,G]
    unsigned short* __restrict__ Wb) // [B,O,T] bf16
{
    __shared__ float ys[B_ * G_];    // 256 floats, block is 256 threads
    ys[threadIdx.x] = y[threadIdx.x];
    __syncthreads();

    const int idx = blockIdx.x * 256 + threadIdx.x;  // over O*T/4
    const int o   = idx >> 8;                        // T/4 = 256 groups per o
    const int t4  = (idx & 255) << 2;

    const float4 m4 = *(const float4*)(mask + (size_t)o * T_ + t4);
    float4 wv[G_];
#pragma unroll
    for (int g = 0; g < G_; ++g) {
        float4 t = *(const float4*)(w + ((size_t)g * O_ + o) * T_ + t4);
        t.x *= m4.x; t.y *= m4.y; t.z *= m4.z; t.w *= m4.w;
        wv[g] = t;
    }
    unsigned short* dst = Wb + (size_t)o * T_ + t4;
#pragma unroll 4
    for (int b = 0; b < B_; ++b) {
        float ax = 0.f, ay = 0.f, az = 0.f, aw = 0.f;
#pragma unroll
        for (int g = 0; g < G_; ++g) {
            const float yv = ys[b * G_ + g];
            ax += yv * wv[g].x; ay += yv * wv[g].y;
            az += yv * wv[g].z; aw += yv * wv[g].w;
        }
        ushort4 pk;
        pk.x = f2bf(ax); pk.y = f2bf(ay); pk.z = f2bf(az); pk.w = f2bf(aw);
        *(ushort4*)(dst + (size_t)b * O_ * T_) = pk;
    }
}

// --- K2: f32 -> bf16 conversion of x (coalesced float4 in, ushort4 out).
__global__ __launch_bounds__(256) void cvt_kernel(
    const float* __restrict__ x, unsigned short* __restrict__ xb)
{
    const int i = blockIdx.x * 256 + threadIdx.x;
    const float4 v = ((const float4*)x)[i];
    ushort4 pk;
    pk.x = f2bf(v.x); pk.y = f2bf(v.y); pk.z = f2bf(v.z); pk.w = f2bf(v.w);
    ((ushort4*)xb)[i] = pk;
}

__device__ __forceinline__ void load16_to_lds(const unsigned short* g, unsigned short* l) {
    __builtin_amdgcn_global_load_lds(
        (const __attribute__((address_space(1))) unsigned char*)g,
        (__attribute__((address_space(3))) unsigned char*)l,
        16, 0, 0);
}

// --- K3: batched GEMM, C = A . B^T, both operands K-major bf16 (m97 structure).
// 128x128 block tile, BK=32, 4 waves in 2x2, each wave 4x4 grid of 16x16x32 MFMA.
__global__ __launch_bounds__(256, 2) void gemm_kernel(
    const unsigned short* __restrict__ xb,   // [B][N_][T_] bf16
    const unsigned short* __restrict__ Wb,   // [B][O_][T_] bf16
    const float* __restrict__ bias,          // [O_]
    float* __restrict__ out)                 // [B][N_][O_] f32
{
    __shared__ __align__(16) unsigned short lA[BM * BK];  // 8 KiB
    __shared__ __align__(16) unsigned short lB[BN * BK];  // 8 KiB

    const int tn = blockIdx.x;   // 0..7   (o tiles)
    const int tm = blockIdx.y;   // 0..1   (n tiles)
    const int b  = blockIdx.z;   // 0..31

    const int tid  = threadIdx.x;
    const int lane = tid & 63;
    const int wave = tid >> 6;
    const int wm   = (wave >> 1) * 64;
    const int wn   = (wave & 1) * 64;

    const unsigned short* Ab = xb + (size_t)b * N_ * T_ + (size_t)(tm * BM) * T_;
    const unsigned short* Bb = Wb + (size_t)b * O_ * T_ + (size_t)(tn * BN) * T_;

    // global_load_lds staging: lane-contiguous LDS, 16 B/lane.
    // byte off = tid*16 (+4096 for chunk 1) -> row = tid/4 (+64), k = (tid&3)*8
    const int srow = tid >> 2;
    const int scol = (tid & 3) * 8;
    const unsigned short* ga0 = Ab + (size_t)srow * T_ + scol;
    const unsigned short* gb0 = Bb + (size_t)srow * T_ + scol;
    unsigned short* la_dst = lA + tid * 8;
    unsigned short* lb_dst = lB + tid * 8;

    f32x4 acc[4][4] = {};

    // fragment read: lane holds row (lane&15), k = (lane>>4)*8 .. +8  (ds_read_b128)
    const int fr = lane & 15;
    const int fq = (lane >> 4) * 8;

    for (int kt = 0; kt < T_; kt += BK) {
        load16_to_lds(ga0 + kt,            la_dst);
        load16_to_lds(ga0 + 64 * T_ + kt,  la_dst + 2048);
        load16_to_lds(gb0 + kt,            lb_dst);
        load16_to_lds(gb0 + 64 * T_ + kt,  lb_dst + 2048);
        __syncthreads();

        bf16x8 afr[4], bfr[4];
#pragma unroll
        for (int i = 0; i < 4; ++i)
            afr[i] = *(const bf16x8*)(lA + (wm + i * 16 + fr) * BK + fq);
#pragma unroll
        for (int i = 0; i < 4; ++i)
            bfr[i] = *(const bf16x8*)(lB + (wn + i * 16 + fr) * BK + fq);

#pragma unroll
        for (int mi = 0; mi < 4; ++mi)
#pragma unroll
            for (int ni = 0; ni < 4; ++ni)
                acc[mi][ni] = __builtin_amdgcn_mfma_f32_16x16x32_bf16(
                    afr[mi], bfr[ni], acc[mi][ni], 0, 0, 0);
        __syncthreads();
    }

    // Epilogue: D[row=(lane>>4)*4+r][col=lane&15] (verified m89/m91 layout) + bias.
    float* outb = out + (size_t)b * N_ * O_ + (size_t)(tm * BM) * O_ + (tn * BN);
    const int cn = lane & 15;
    const int cr = (lane >> 4) * 4;
#pragma unroll
    for (int ni = 0; ni < 4; ++ni) {
        const int col = wn + ni * 16 + cn;
        const float bv = bias[tn * BN + col];
#pragma unroll
        for (int mi = 0; mi < 4; ++mi) {
#pragma unroll
            for (int r = 0; r < 4; ++r) {
                const int row = wm + mi * 16 + cr + r;
                outb[(size_t)row * O_ + col] = acc[mi][ni][r] + bv;
            }
        }
    }
}

// --- Fallback (only if ws_size is too small for Wb+xb): correct, fp32, slow.
__global__ __launch_bounds__(256) void naive_kernel(
    const float* __restrict__ x, const float* __restrict__ y,
    const float* __restrict__ w, const float* __restrict__ mask,
    const float* __restrict__ bias, float* __restrict__ out)
{
    const int oc = blockIdx.x & 3;
    const int n  = (blockIdx.x >> 2) & (N_ - 1);
    const int b  = blockIdx.x >> 10;

    __shared__ float xs[T_];
    __shared__ float ys[G_];
    const float* xrow = x + ((size_t)b * N_ + n) * T_;
    for (int i = threadIdx.x; i < T_ / 4; i += 256)
        ((float4*)xs)[i] = ((const float4*)xrow)[i];
    if (threadIdx.x < G_) ys[threadIdx.x] = y[b * G_ + threadIdx.x];
    __syncthreads();

    const int o = oc * 256 + threadIdx.x;
    float acc = 0.f;
    for (int t = 0; t < T_; t += 4) {
        const float4 m4 = *(const float4*)(mask + (size_t)o * T_ + t);
        float4 s = {0.f, 0.f, 0.f, 0.f};
#pragma unroll
        for (int g = 0; g < G_; ++g) {
            const float4 w4 = *(const float4*)(w + ((size_t)g * O_ + o) * T_ + t);
            const float yv = ys[g];
            s.x += yv * w4.x; s.y += yv * w4.y; s.z += yv * w4.z; s.w += yv * w4.w;
        }
        acc += xs[t] * m4.x * s.x + xs[t + 1] * m4.y * s.y
             + xs[t + 2] * m4.z * s.z + xs[t + 3] * m4.w * s.w;
    }
    out[((size_t)b * N_ + n) * O_ + o] = acc + bias[o];
}

extern "C" void kernel_launch(void* const* d_in, const int* in_sizes, int n_in,
                              void* d_out, int out_size, void* d_ws, size_t ws_size,
                              hipStream_t stream) {
    const float* x    = (const float*)d_in[0];
    const float* y    = (const float*)d_in[1];
    const float* w    = (const float*)d_in[2];
    const float* mask = (const float*)d_in[3];
    const float* bias = (const float*)d_in[4];
    float* out = (float*)d_out;

    const size_t wb_bytes = (size_t)B_ * O_ * T_ * sizeof(unsigned short); // 64 MiB
    const size_t xb_bytes = (size_t)B_ * N_ * T_ * sizeof(unsigned short); // 16 MiB

    if (ws_size >= wb_bytes + xb_bytes) {
        unsigned short* Wb = (unsigned short*)d_ws;
        unsigned short* xb = (unsigned short*)((char*)d_ws + wb_bytes);
        mix_kernel<<<O_ * T_ / 4 / 256, 256, 0, stream>>>(w, mask, y, Wb);
        cvt_kernel<<<B_ * N_ * T_ / 4 / 256, 256, 0, stream>>>(x, xb);
        dim3 grid(O_ / BN, N_ / BM, B_);
        gemm_kernel<<<grid, 256, 0, stream>>>(xb, Wb, bias, out);
    } else {
        naive_kernel<<<B_ * N_ * (O_ / 256), 256, 0, stream>>>(x, y, w, mask, bias, out);
    }
}

// Round 2
// 165.344 us; speedup vs baseline: 1.0219x; 1.0219x over previous
//
#include <hip/hip_runtime.h>
#include <hip/hip_bf16.h>
#include <stdint.h>

// out[b,n,o] = sum_t x[b,n,t] * (sum_g y[b,g]*w[g,o,t]*mask[o,t]) + bias[o]
// B=32 N=256 T=1024 O=1024 G=8.  bf16 MFMA path (absmax 0.031 vs thr 0.154, R1).
//
//  K1 prep: fused  Wb[b,o,t]=bf16(mask*sum_g y*w)  AND  xb=bf16(x)
//  K2 gemm: out[b] = xb[b] . Wb[b]^T + bias
//           128x128 tile, BK=64 (32 MFMA/barrier), XOR-swizzled LDS (conflict-free)

#define B_ 32
#define N_ 256
#define T_ 1024
#define O_ 1024
#define G_ 8

#define BM 128
#define BN 128
#define BK 64   // elements; LDS row = 128 B = 8 chunks of 16 B

typedef __attribute__((__ext_vector_type__(8))) __bf16 bf16x8;
typedef __attribute__((__ext_vector_type__(4))) float  f32x4;

__device__ __forceinline__ unsigned short f2bf(float f) {
    union { float f; uint32_t u; } v; v.f = f;
    uint32_t u = v.u;
    uint32_t r = (u + 0x7fffu + ((u >> 16) & 1u)) >> 16;  // RNE
    return (unsigned short)r;
}

#define MIX_BLOCKS (O_ * T_ / 4 / 256)          // 1024
#define CVT_BLOCKS (B_ * N_ * T_ / 4 / 256)     // 8192

// --- K1: fused prologue. Blocks [0,1024): genre-mix+mask -> Wb bf16 (w read once,
// loop all 32 batches). Blocks [1024, 9216): x f32 -> bf16.
__global__ __launch_bounds__(256) void prep_kernel(
    const float* __restrict__ w,     // [G,O,T]
    const float* __restrict__ mask,  // [O,T]
    const float* __restrict__ y,     // [B,G]
    const float* __restrict__ x,     // [B,N,T]
    unsigned short* __restrict__ Wb, // [B,O,T] bf16
    unsigned short* __restrict__ xb) // [B,N,T] bf16
{
    if (blockIdx.x < MIX_BLOCKS) {
        __shared__ float ys[B_ * G_];
        ys[threadIdx.x] = y[threadIdx.x];
        __syncthreads();

        const int idx = blockIdx.x * 256 + threadIdx.x;  // over O*T/4
        const int o   = idx >> 8;
        const int t4  = (idx & 255) << 2;

        const float4 m4 = *(const float4*)(mask + (size_t)o * T_ + t4);
        float4 wv[G_];
#pragma unroll
        for (int g = 0; g < G_; ++g) {
            float4 t = *(const float4*)(w + ((size_t)g * O_ + o) * T_ + t4);
            t.x *= m4.x; t.y *= m4.y; t.z *= m4.z; t.w *= m4.w;
            wv[g] = t;
        }
        unsigned short* dst = Wb + (size_t)o * T_ + t4;
#pragma unroll 4
        for (int b = 0; b < B_; ++b) {
            float ax = 0.f, ay = 0.f, az = 0.f, aw = 0.f;
#pragma unroll
            for (int g = 0; g < G_; ++g) {
                const float yv = ys[b * G_ + g];
                ax += yv * wv[g].x; ay += yv * wv[g].y;
                az += yv * wv[g].z; aw += yv * wv[g].w;
            }
            ushort4 pk;
            pk.x = f2bf(ax); pk.y = f2bf(ay); pk.z = f2bf(az); pk.w = f2bf(aw);
            *(ushort4*)(dst + (size_t)b * O_ * T_) = pk;
        }
    } else {
        const int i = (blockIdx.x - MIX_BLOCKS) * 256 + threadIdx.x;
        const float4 v = ((const float4*)x)[i];
        ushort4 pk;
        pk.x = f2bf(v.x); pk.y = f2bf(v.y); pk.z = f2bf(v.z); pk.w = f2bf(v.w);
        ((ushort4*)xb)[i] = pk;
    }
}

__device__ __forceinline__ void load16_to_lds(const unsigned short* g, unsigned short* l) {
    __builtin_amdgcn_global_load_lds(
        (const __attribute__((address_space(1))) unsigned char*)g,
        (__attribute__((address_space(3))) unsigned char*)l,
        16, 0, 0);
}

// --- K2: batched GEMM, C = A . B^T, K-major bf16 both sides.
// LDS layout [row][chunk], where LDS chunk c holds GLOBAL chunk (c ^ (row&7)).
// global_load_lds forces lane-contiguous LDS (m104/m108), so the swizzle is
// applied to the per-lane GLOBAL source column; ds_read side XORs it back.
// Result: every ds_read_b128 16-lane phase spreads over all 8 bank-groups
// (2 lanes each = free, m136) instead of 8-way conflicting.
__global__ __launch_bounds__(256, 2) void gemm_kernel(
    const unsigned short* __restrict__ xb,   // [B][N_][T_] bf16
    const unsigned short* __restrict__ Wb,   // [B][O_][T_] bf16
    const float* __restrict__ bias,          // [O_]
    float* __restrict__ out)                 // [B][N_][O_] f32
{
    __shared__ __align__(16) unsigned short lA[BM * BK];  // 16 KiB
    __shared__ __align__(16) unsigned short lB[BN * BK];  // 16 KiB

    const int tn = blockIdx.x;   // 0..7  (o tiles)
    const int tm = blockIdx.y;   // 0..1  (n tiles)
    const int b  = blockIdx.z;   // 0..31

    const int tid  = threadIdx.x;
    const int lane = tid & 63;
    const int wave = tid >> 6;
    const int wm   = (wave >> 1) * 64;
    const int wn   = (wave & 1) * 64;

    const unsigned short* Ab = xb + (size_t)b * N_ * T_ + (size_t)(tm * BM) * T_;
    const unsigned short* Bb = Wb + (size_t)b * O_ * T_ + (size_t)(tn * BN) * T_;

    // Staging: round i in 0..3, LDS elem = tid*8 + i*2048 -> row = tid/8 + i*32,
    // chunkpos = tid&7. Source global chunk = chunkpos ^ (row&7); (i*32)&7==0 so
    // the XOR term is round-invariant.
    const int srow   = tid >> 3;                       // 0..31
    const int schunk = (tid & 7) ^ (srow & 7);
    const unsigned short* ga0 = Ab + (size_t)srow * T_ + schunk * 8;
    const unsigned short* gb0 = Bb + (size_t)srow * T_ + schunk * 8;
    unsigned short* la_dst = lA + tid * 8;
    unsigned short* lb_dst = lB + tid * 8;

    f32x4 acc[4][4] = {};

    const int fr = lane & 15;       // fragment row within 16
    const int q  = lane >> 4;       // 0..3 -> k-quad
    const int sw = fr & 7;          // swizzle term (row&7 == fr&7: wm,i*16 are mult of 8)

    for (int kt = 0; kt < T_; kt += BK) {
#pragma unroll
        for (int i = 0; i < 4; ++i) {
            load16_to_lds(ga0 + kt + (size_t)(i * 32) * T_, la_dst + i * 2048);
            load16_to_lds(gb0 + kt + (size_t)(i * 32) * T_, lb_dst + i * 2048);
        }
        __syncthreads();

#pragma unroll
        for (int kk = 0; kk < 2; ++kk) {
            const int cp = ((kk * 4 + q) ^ sw) * 8;    // physical chunk offset (elems)
            bf16x8 afr[4], bfr[4];
#pragma unroll
            for (int i = 0; i < 4; ++i)
                afr[i] = *(const bf16x8*)(lA + (wm + i * 16 + fr) * BK + cp);
#pragma unroll
            for (int i = 0; i < 4; ++i)
                bfr[i] = *(const bf16x8*)(lB + (wn + i * 16 + fr) * BK + cp);
#pragma unroll
            for (int mi = 0; mi < 4; ++mi)
#pragma unroll
                for (int ni = 0; ni < 4; ++ni)
                    acc[mi][ni] = __builtin_amdgcn_mfma_f32_16x16x32_bf16(
                        afr[mi], bfr[ni], acc[mi][ni], 0, 0, 0);
        }
        __syncthreads();
    }

    // Epilogue: D[row=(lane>>4)*4+r][col=lane&15] (m89/m91 layout) + bias.
    float* outb = out + (size_t)b * N_ * O_ + (size_t)(tm * BM) * O_ + (tn * BN);
    const int cn = lane & 15;
    const int cr = (lane >> 4) * 4;
#pragma unroll
    for (int ni = 0; ni < 4; ++ni) {
        const int col = wn + ni * 16 + cn;
        const float bv = bias[tn * BN + col];
#pragma unroll
        for (int mi = 0; mi < 4; ++mi) {
#pragma unroll
            for (int r = 0; r < 4; ++r) {
                const int row = wm + mi * 16 + cr + r;
                outb[(size_t)row * O_ + col] = acc[mi][ni][r] + bv;
            }
        }
    }
}

// --- Fallback (ws too small): correct fp32 path.
__global__ __launch_bounds__(256) void naive_kernel(
    const float* __restrict__ x, const float* __restrict__ y,
    const float* __restrict__ w, const float* __restrict__ mask,
    const float* __restrict__ bias, float* __restrict__ out)
{
    const int oc = blockIdx.x & 3;
    const int n  = (blockIdx.x >> 2) & (N_ - 1);
    const int b  = blockIdx.x >> 10;

    __shared__ float xs[T_];
    __shared__ float ys[G_];
    const float* xrow = x + ((size_t)b * N_ + n) * T_;
    for (int i = threadIdx.x; i < T_ / 4; i += 256)
        ((float4*)xs)[i] = ((const float4*)xrow)[i];
    if (threadIdx.x < G_) ys[threadIdx.x] = y[b * G_ + threadIdx.x];
    __syncthreads();

    const int o = oc * 256 + threadIdx.x;
    float acc = 0.f;
    for (int t = 0; t < T_; t += 4) {
        const float4 m4 = *(const float4*)(mask + (size_t)o * T_ + t);
        float4 s = {0.f, 0.f, 0.f, 0.f};
#pragma unroll
        for (int g = 0; g < G_; ++g) {
            const float4 w4 = *(const float4*)(w + ((size_t)g * O_ + o) * T_ + t);
            const float yv = ys[g];
            s.x += yv * w4.x; s.y += yv * w4.y; s.z += yv * w4.z; s.w += yv * w4.w;
        }
        acc += xs[t] * m4.x * s.x + xs[t + 1] * m4.y * s.y
             + xs[t + 2] * m4.z * s.z + xs[t + 3] * m4.w * s.w;
    }
    out[((size_t)b * N_ + n) * O_ + o] = acc + bias[o];
}

extern "C" void kernel_launch(void* const* d_in, const int* in_sizes, int n_in,
                              void* d_out, int out_size, void* d_ws, size_t ws_size,
                              hipStream_t stream) {
    const float* x    = (const float*)d_in[0];
    const float* y    = (const float*)d_in[1];
    const float* w    = (const float*)d_in[2];
    const float* mask = (const float*)d_in[3];
    const float* bias = (const float*)d_in[4];
    float* out = (float*)d_out;

    const size_t wb_bytes = (size_t)B_ * O_ * T_ * sizeof(unsigned short); // 64 MiB
    const size_t xb_bytes = (size_t)B_ * N_ * T_ * sizeof(unsigned short); // 16 MiB

    if (ws_size >= wb_bytes + xb_bytes) {
        unsigned short* Wb = (unsigned short*)d_ws;
        unsigned short* xb = (unsigned short*)((char*)d_ws + wb_bytes);
        prep_kernel<<<MIX_BLOCKS + CVT_BLOCKS, 256, 0, stream>>>(w, mask, y, x, Wb, xb);
        dim3 grid(O_ / BN, N_ / BM, B_);
        gemm_kernel<<<grid, 256, 0, stream>>>(xb, Wb, bias, out);
    } else {
        naive_kernel<<<B_ * N_ * (O_ / 256), 256, 0, stream>>>(x, y, w, mask, bias, out);
    }
}

// Round 3
// 163.406 us; speedup vs baseline: 1.0340x; 1.0119x over previous
//
#include <hip/hip_runtime.h>
#include <hip/hip_bf16.h>
#include <stdint.h>

// out[b,n,o] = sum_t x[b,n,t] * (sum_g y[b,g]*w[g,o,t]*mask[o,t]) + bias[o]
// B=32 N=256 T=1024 O=1024 G=8.  bf16 MFMA path (absmax 0.031 vs thr 0.154).
//
//  K1 prep: mix blocks (512): Wb[b,o,t]=bf16(mask*sum_g y*w), 16B stores,
//           thread owns 8 t, loops 32 b, w read once.  cvt blocks (1024): xb=bf16(x).
//  K2 gemm: out[b] = xb[b] . Wb[b]^T + bias.  128x128 tile, BK=64,
//           XOR-swizzled LDS, DOUBLE-BUFFERED global_load_lds prefetch.

#define B_ 32
#define N_ 256
#define T_ 1024
#define O_ 1024
#define G_ 8

#define BM 128
#define BN 128
#define BK 64            // elems; LDS row = 128 B = 8 x 16 B chunks
#define BUFSZ (BM * BK)  // 8192 elems = 16 KiB

typedef __attribute__((__ext_vector_type__(8))) __bf16 bf16x8;
typedef __attribute__((__ext_vector_type__(4))) float  f32x4;

__device__ __forceinline__ unsigned short f2bf(float f) {
    union { float f; uint32_t u; } v; v.f = f;
    uint32_t u = v.u;
    uint32_t r = (u + 0x7fffu + ((u >> 16) & 1u)) >> 16;  // RNE
    return (unsigned short)r;
}

__device__ __forceinline__ uint4 pack8(const float* a) {
    uint4 r;
    r.x = (uint32_t)f2bf(a[0]) | ((uint32_t)f2bf(a[1]) << 16);
    r.y = (uint32_t)f2bf(a[2]) | ((uint32_t)f2bf(a[3]) << 16);
    r.z = (uint32_t)f2bf(a[4]) | ((uint32_t)f2bf(a[5]) << 16);
    r.w = (uint32_t)f2bf(a[6]) | ((uint32_t)f2bf(a[7]) << 16);
    return r;
}

#define MIXB 512    // mix: O*T/8 threads / 256 = 512 blocks (2 o-rows each)
#define CVTB 1024   // cvt: 262144 threads, 8 float4 each (4 steps x 2)

// --- K1: fused prologue.
__global__ __launch_bounds__(256) void prep_kernel(
    const float* __restrict__ w,     // [G,O,T]
    const float* __restrict__ mask,  // [O,T]
    const float* __restrict__ y,     // [B,G]
    const float* __restrict__ x,     // [B,N,T]
    unsigned short* __restrict__ Wb, // [B,O,T] bf16
    unsigned short* __restrict__ xb) // [B,N,T] bf16
{
    const int tid = threadIdx.x;
    if (blockIdx.x < MIXB) {
        // thread -> (o, 8 consecutive t)
        const int o = blockIdx.x * 2 + (tid >> 7);
        const int t = (tid & 127) * 8;

        const float* mp = mask + (size_t)o * T_ + t;
        const float4 m0 = *(const float4*)(mp);
        const float4 m1 = *(const float4*)(mp + 4);

        float wv[G_][8];
#pragma unroll
        for (int g = 0; g < G_; ++g) {
            const float* wp = w + ((size_t)g * O_ + o) * T_ + t;
            const float4 a = *(const float4*)(wp);
            const float4 c = *(const float4*)(wp + 4);
            wv[g][0] = a.x * m0.x; wv[g][1] = a.y * m0.y;
            wv[g][2] = a.z * m0.z; wv[g][3] = a.w * m0.w;
            wv[g][4] = c.x * m1.x; wv[g][5] = c.y * m1.y;
            wv[g][6] = c.z * m1.z; wv[g][7] = c.w * m1.w;
        }
        unsigned short* dst = Wb + (size_t)o * T_ + t;
        for (int b = 0; b < B_; ++b) {
            // wave-uniform y reads -> scalar loads, no LDS
            const float4 y0 = *(const float4*)(y + b * G_);
            const float4 y1 = *(const float4*)(y + b * G_ + 4);
            const float yv[G_] = {y0.x, y0.y, y0.z, y0.w, y1.x, y1.y, y1.z, y1.w};
            float acc[8] = {};
#pragma unroll
            for (int g = 0; g < G_; ++g)
#pragma unroll
                for (int j = 0; j < 8; ++j)
                    acc[j] += yv[g] * wv[g][j];
            *(uint4*)(dst + (size_t)b * O_ * T_) = pack8(acc);
        }
    } else {
        // cvt: 8 float4 per thread (2 consecutive per step, 4 strided steps)
        const int i = (blockIdx.x - MIXB) * 256 + tid;
        const float4* x4 = (const float4*)x;
        uint4* o4 = (uint4*)xb;
#pragma unroll
        for (int j = 0; j < 4; ++j) {
            const size_t f4 = (size_t)j * 524288 + (size_t)i * 2;
            const float4 a = x4[f4];
            const float4 b = x4[f4 + 1];
            const float v[8] = {a.x, a.y, a.z, a.w, b.x, b.y, b.z, b.w};
            o4[(size_t)j * 262144 + i] = pack8(v);
        }
    }
}

__device__ __forceinline__ void load16_to_lds(const unsigned short* g, unsigned short* l) {
    __builtin_amdgcn_global_load_lds(
        (const __attribute__((address_space(1))) unsigned char*)g,
        (__attribute__((address_space(3))) unsigned char*)l,
        16, 0, 0);
}

// --- K2: batched GEMM, C = A . B^T, K-major bf16 both sides.
// LDS chunk c of row r holds global chunk (c ^ (r&7)) -> ds_read_b128 phases
// spread over all 8 bank-groups (2 lanes each = free, m136).
// Double-buffered: stage(kt+1) issued right after the barrier, so the
// global_load_lds latency is hidden behind ds_read+MFMA of tile kt; the
// compiler's vmcnt(0)-before-barrier drains it one full tile later.
__global__ __launch_bounds__(256, 2) void gemm_kernel(
    const unsigned short* __restrict__ xb,   // [B][N_][T_] bf16
    const unsigned short* __restrict__ Wb,   // [B][O_][T_] bf16
    const float* __restrict__ bias,          // [O_]
    float* __restrict__ out)                 // [B][N_][O_] f32
{
    __shared__ __align__(16) unsigned short lA[2 * BUFSZ];  // 32 KiB
    __shared__ __align__(16) unsigned short lB[2 * BUFSZ];  // 32 KiB

    const int tn = blockIdx.x;   // 0..7  (o tiles)
    const int tm = blockIdx.y;   // 0..1  (n tiles)
    const int b  = blockIdx.z;   // 0..31

    const int tid  = threadIdx.x;
    const int lane = tid & 63;
    const int wave = tid >> 6;
    const int wm   = (wave >> 1) * 64;
    const int wn   = (wave & 1) * 64;

    const unsigned short* Ab = xb + (size_t)b * N_ * T_ + (size_t)(tm * BM) * T_;
    const unsigned short* Bb = Wb + (size_t)b * O_ * T_ + (size_t)(tn * BN) * T_;

    // staging: round i: LDS elem tid*8 + i*2048 -> row tid/8 + i*32, chunk tid&7
    const int srow   = tid >> 3;
    const int schunk = (tid & 7) ^ (srow & 7);
    const unsigned short* ga0 = Ab + (size_t)srow * T_ + schunk * 8;
    const unsigned short* gb0 = Bb + (size_t)srow * T_ + schunk * 8;

#define STAGE(buf, kt)                                                          \
    {                                                                           \
        unsigned short* lad = lA + (buf) * BUFSZ + tid * 8;                     \
        unsigned short* lbd = lB + (buf) * BUFSZ + tid * 8;                     \
        _Pragma("unroll")                                                       \
        for (int i_ = 0; i_ < 4; ++i_) {                                        \
            load16_to_lds(ga0 + (kt) + (size_t)(i_ * 32) * T_, lad + i_ * 2048);\
            load16_to_lds(gb0 + (kt) + (size_t)(i_ * 32) * T_, lbd + i_ * 2048);\
        }                                                                       \
    }

    f32x4 acc[4][4] = {};

    const int fr = lane & 15;       // fragment row within 16
    const int q  = lane >> 4;       // k-quad 0..3
    const int sw = fr & 7;          // row&7 (wm, i*16 are multiples of 8)

#define COMPUTE(buf)                                                            \
    {                                                                           \
        const unsigned short* la = lA + (buf) * BUFSZ;                          \
        const unsigned short* lb = lB + (buf) * BUFSZ;                          \
        _Pragma("unroll")                                                       \
        for (int kk = 0; kk < 2; ++kk) {                                        \
            const int cp = ((kk * 4 + q) ^ sw) * 8;                             \
            bf16x8 afr[4], bfr[4];                                              \
            _Pragma("unroll")                                                   \
            for (int i_ = 0; i_ < 4; ++i_)                                      \
                afr[i_] = *(const bf16x8*)(la + (wm + i_ * 16 + fr) * BK + cp); \
            _Pragma("unroll")                                                   \
            for (int i_ = 0; i_ < 4; ++i_)                                      \
                bfr[i_] = *(const bf16x8*)(lb + (wn + i_ * 16 + fr) * BK + cp); \
            _Pragma("unroll")                                                   \
            for (int mi = 0; mi < 4; ++mi)                                      \
                _Pragma("unroll")                                               \
                for (int ni = 0; ni < 4; ++ni)                                  \
                    acc[mi][ni] = __builtin_amdgcn_mfma_f32_16x16x32_bf16(      \
                        afr[mi], bfr[ni], acc[mi][ni], 0, 0, 0);                \
        }                                                                       \
    }

    STAGE(0, 0)
    for (int kt = 0; kt < T_; kt += 2 * BK) {
        __syncthreads();                       // buf0(kt) staged (vmcnt drained)
        STAGE(1, kt + BK)                      // prefetch buf1
        COMPUTE(0)
        __syncthreads();                       // buf1 staged; all reads of buf0 done
        if (kt + 2 * BK < T_) STAGE(0, kt + 2 * BK)
        COMPUTE(1)
    }

    // Epilogue: D[row=(lane>>4)*4+r][col=lane&15] (m89/m91) + bias.
    float* outb = out + (size_t)b * N_ * O_ + (size_t)(tm * BM) * O_ + (tn * BN);
    const int cn = lane & 15;
    const int cr = (lane >> 4) * 4;
#pragma unroll
    for (int ni = 0; ni < 4; ++ni) {
        const int col = wn + ni * 16 + cn;
        const float bv = bias[tn * BN + col];
#pragma unroll
        for (int mi = 0; mi < 4; ++mi) {
#pragma unroll
            for (int r = 0; r < 4; ++r) {
                const int row = wm + mi * 16 + cr + r;
                outb[(size_t)row * O_ + col] = acc[mi][ni][r] + bv;
            }
        }
    }
}

// --- Fallback (ws too small): correct fp32 path.
__global__ __launch_bounds__(256) void naive_kernel(
    const float* __restrict__ x, const float* __restrict__ y,
    const float* __restrict__ w, const float* __restrict__ mask,
    const float* __restrict__ bias, float* __restrict__ out)
{
    const int oc = blockIdx.x & 3;
    const int n  = (blockIdx.x >> 2) & (N_ - 1);
    const int b  = blockIdx.x >> 10;

    __shared__ float xs[T_];
    __shared__ float ys[G_];
    const float* xrow = x + ((size_t)b * N_ + n) * T_;
    for (int i = threadIdx.x; i < T_ / 4; i += 256)
        ((float4*)xs)[i] = ((const float4*)xrow)[i];
    if (threadIdx.x < G_) ys[threadIdx.x] = y[b * G_ + threadIdx.x];
    __syncthreads();

    const int o = oc * 256 + threadIdx.x;
    float acc = 0.f;
    for (int t = 0; t < T_; t += 4) {
        const float4 m4 = *(const float4*)(mask + (size_t)o * T_ + t);
        float4 s = {0.f, 0.f, 0.f, 0.f};
#pragma unroll
        for (int g = 0; g < G_; ++g) {
            const float4 w4 = *(const float4*)(w + ((size_t)g * O_ + o) * T_ + t);
            const float yv = ys[g];
            s.x += yv * w4.x; s.y += yv * w4.y; s.z += yv * w4.z; s.w += yv * w4.w;
        }
        acc += xs[t] * m4.x * s.x + xs[t + 1] * m4.y * s.y
             + xs[t + 2] * m4.z * s.z + xs[t + 3] * m4.w * s.w;
    }
    out[((size_t)b * N_ + n) * O_ + o] = acc + bias[o];
}

extern "C" void kernel_launch(void* const* d_in, const int* in_sizes, int n_in,
                              void* d_out, int out_size, void* d_ws, size_t ws_size,
                              hipStream_t stream) {
    const float* x    = (const float*)d_in[0];
    const float* y    = (const float*)d_in[1];
    const float* w    = (const float*)d_in[2];
    const float* mask = (const float*)d_in[3];
    const float* bias = (const float*)d_in[4];
    float* out = (float*)d_out;

    const size_t wb_bytes = (size_t)B_ * O_ * T_ * sizeof(unsigned short); // 64 MiB
    const size_t xb_bytes = (size_t)B_ * N_ * T_ * sizeof(unsigned short); // 16 MiB

    if (ws_size >= wb_bytes + xb_bytes) {
        unsigned short* Wb = (unsigned short*)d_ws;
        unsigned short* xb = (unsigned short*)((char*)d_ws + wb_bytes);
        prep_kernel<<<MIXB + CVTB, 256, 0, stream>>>(w, mask, y, x, Wb, xb);
        dim3 grid(O_ / BN, N_ / BM, B_);
        gemm_kernel<<<grid, 256, 0, stream>>>(xb, Wb, bias, out);
    } else {
        naive_kernel<<<B_ * N_ * (O_ / 256), 256, 0, stream>>>(x, y, w, mask, bias, out);
    }
}